// Round 6
// baseline (140.360 us; speedup 1.0000x reference)
//
#include <hip/hip_runtime.h>
#include <hip/hip_bf16.h>

#define HID   64
#define BLOCK 256
#define GPW   8      // 16-token groups per wave; block covers 64*GPW = 512 tokens

typedef short short8 __attribute__((ext_vector_type(8)));
typedef float floatx4 __attribute__((ext_vector_type(4)));

// two float4 -> bf16 short8 via packed RNE cvt
__device__ __forceinline__ short8 cvt8f(float4 f0, float4 f1) {
    union { __hip_bfloat162 h[4]; short8 s; } r;
    r.h[0] = __float22bfloat162_rn(make_float2(f0.x, f0.y));
    r.h[1] = __float22bfloat162_rn(make_float2(f0.z, f0.w));
    r.h[2] = __float22bfloat162_rn(make_float2(f1.x, f1.y));
    r.h[3] = __float22bfloat162_rn(make_float2(f1.z, f1.w));
    return r.s;
}

__device__ __forceinline__ void gload_lds16(const float* g, float* l) {
    __builtin_amdgcn_global_load_lds(
        (const __attribute__((address_space(1))) void*)g,
        (__attribute__((address_space(3))) void*)l, 16, 0, 0);
}

// Stage this wave's 16-token slab (4 KB) for tile g into per-wave buffer b.
// Consumption-order layout (rule 21: pre-swizzled GLOBAL src, linear LDS dest):
// chunk c = kc*2+half; slot (c,lane) = x[tok(r15)][kg*8 + kc*32 + half*4 .. +4)
#define STAGE(g, b) do {                                                          \
    _Pragma("unroll")                                                             \
    for (int c = 0; c < 4; ++c) {                                                 \
        const int kc_ = c >> 1, hf_ = c & 1;                                      \
        const float* src_ = x + (tok0 + (long)(g) * 64 + r15) * HID               \
                              + kg * 8 + kc_ * 32 + hf_ * 4;                      \
        gload_lds16(src_, &sbuf[wave][(b)][c * 256]);                             \
    } } while (0)

// Compute tile g from buffer b: 16 tokens x 64 cols, all 3 modalities, select.
#define COMPUTE(g, b) do {                                                        \
    const float4 q0 = *(const float4*)&sbuf[wave][(b)][0 * 256 + lane * 4];       \
    const float4 q1 = *(const float4*)&sbuf[wave][(b)][1 * 256 + lane * 4];       \
    const float4 q2 = *(const float4*)&sbuf[wave][(b)][2 * 256 + lane * 4];       \
    const float4 q3 = *(const float4*)&sbuf[wave][(b)][3 * 256 + lane * 4];       \
    const short8 xb0 = cvt8f(q0, q1);                                             \
    const short8 xb1 = cvt8f(q2, q3);                                             \
    const int m_ = mreg[(g)];                                                     \
    float* ob_ = out + (tok0 + (long)(g) * 64 + r15) * HID + kg * 4;              \
    _Pragma("unroll")                                                             \
    for (int nt = 0; nt < 4; ++nt) {                                              \
        floatx4 a0 = {0.f,0.f,0.f,0.f}, a1 = {0.f,0.f,0.f,0.f},                   \
                a2 = {0.f,0.f,0.f,0.f};                                           \
        a0 = __builtin_amdgcn_mfma_f32_16x16x32_bf16(wa[0][nt][0], xb0, a0,0,0,0);\
        a0 = __builtin_amdgcn_mfma_f32_16x16x32_bf16(wa[0][nt][1], xb1, a0,0,0,0);\
        a1 = __builtin_amdgcn_mfma_f32_16x16x32_bf16(wa[1][nt][0], xb0, a1,0,0,0);\
        a1 = __builtin_amdgcn_mfma_f32_16x16x32_bf16(wa[1][nt][1], xb1, a1,0,0,0);\
        a2 = __builtin_amdgcn_mfma_f32_16x16x32_bf16(wa[2][nt][0], xb0, a2,0,0,0);\
        a2 = __builtin_amdgcn_mfma_f32_16x16x32_bf16(wa[2][nt][1], xb1, a2,0,0,0);\
        const floatx4 v_ = (m_ == 0) ? a0 : ((m_ == 1) ? a1 : a2);                \
        *(floatx4*)(ob_ + nt * 16) = v_;                                          \
    } } while (0)

#define SB __builtin_amdgcn_sched_barrier(0)

// Steady-state step: prefetch tile g+1, wait exactly for tile g's 4 stage loads
// (younger: 4 prev stores + 4 new stage loads = vmcnt(8), never drains prefetch).
#define STEP(g)                                                                   \
    STAGE((g) + 1, ((g) + 1) & 1); SB;                                            \
    asm volatile("s_waitcnt vmcnt(8)" ::: "memory"); SB;                          \
    COMPUTE((g), (g) & 1); SB;

__global__ __launch_bounds__(BLOCK) void moe_wavepipe(
    const float* __restrict__ x,
    const float* __restrict__ W,
    const int* __restrict__ mod,
    float* __restrict__ out)
{
    __shared__ float sbuf[4][2][1024];   // [wave][buf][16 tok * 64 f] = 32 KB

    const int tid  = threadIdx.x;
    const int wave = tid >> 6;
    const int lane = tid & 63;
    const int r15  = lane & 15;          // token index within wave's 16
    const int kg   = lane >> 4;          // k-group 0..3

    const long tok0 = (long)blockIdx.x * (64 * GPW) + wave * 16;

    // ---- prologue: mod for all GPW tiles (pinned early), W fragments ----
    int mreg[GPW];
#pragma unroll
    for (int g = 0; g < GPW; ++g)
        mreg[g] = mod[tok0 + g * 64 + r15];
    asm volatile("" :: "v"(mreg[0]), "v"(mreg[1]), "v"(mreg[2]), "v"(mreg[3]),
                       "v"(mreg[4]), "v"(mreg[5]), "v"(mreg[6]), "v"(mreg[7]));

    // A-fragments = W rows for ALL 64 output cols (4 col-tiles), 3 modalities
    short8 wa[3][4][2];
#pragma unroll
    for (int mm = 0; mm < 3; ++mm)
#pragma unroll
        for (int nt = 0; nt < 4; ++nt) {
            const float* wp = W + mm * 4096 + (nt * 16 + r15) * HID + kg * 8;
            wa[mm][nt][0] = cvt8f(*(const float4*)wp,        *(const float4*)(wp + 4));
            wa[mm][nt][1] = cvt8f(*(const float4*)(wp + 32), *(const float4*)(wp + 36));
        }

    STAGE(0, 0); SB;
    STAGE(1, 1); SB;
    asm volatile("s_waitcnt vmcnt(4)" ::: "memory"); SB;   // tile 0 ready
    COMPUTE(0, 0); SB;

    STEP(1) STEP(2) STEP(3) STEP(4) STEP(5) STEP(6)

    asm volatile("s_waitcnt vmcnt(4)" ::: "memory"); SB;   // tile 7 ready (4 younger stores)
    COMPUTE(7, 1);
}

extern "C" void kernel_launch(void* const* d_in, const int* in_sizes, int n_in,
                              void* d_out, int out_size, void* d_ws, size_t ws_size,
                              hipStream_t stream) {
    const float* x   = (const float*)d_in[0];
    const float* W   = (const float*)d_in[1];
    const int*   mod = (const int*)d_in[2];
    float*       out = (float*)d_out;

    const int n      = in_sizes[0] / HID;     // tokens (1<<20)
    const int blocks = n / (64 * GPW);        // 2048

    moe_wavepipe<<<blocks, BLOCK, 0, stream>>>(x, W, mod, out);
}